// Round 1
// baseline (664.073 us; speedup 1.0000x reference)
//
#include <hip/hip_runtime.h>

#define NCLASS 1000
#define HALF 32                      // dims per dim-group (64 total, split 2 ways)
#define ACC_WORDS (NCLASS * HALF)    // 32000 floats per partial slot (128 KB)
#define WARMUP 1000

// ---------------------------------------------------------------------------
// zero a float region (also used for int counts: 0 bit pattern)
__global__ void bank_zero_kernel(float* __restrict__ p, int n) {
    int i = blockIdx.x * blockDim.x + threadIdx.x;
    if (i < n) p[i] = 0.0f;
}

// ---------------------------------------------------------------------------
// Per-block LDS-privatized segment sum over a contiguous row chunk.
// blockIdx.x = chunk*2 + dim_group. 512 threads: 8 lanes per row (float4 each),
// 64 rows per block-iteration. LDS word index XOR-swizzled by (label&31) so
// ds_add_f32 banks are randomized (fixed mapping would be 8-way conflicted).
__global__ __launch_bounds__(512)
void bank_accum_kernel(const float* __restrict__ feat,
                       const int* __restrict__ label,
                       int n, int rows_per_chunk, int nchunk,
                       float* __restrict__ psums,   // partial slots OR [NCLASS][64] global acc
                       int* __restrict__ counts,
                       int atomic_mode)
{
    __shared__ float table[ACC_WORDS];   // 128 KB
    __shared__ int   hist[NCLASS];       // 4 KB (used by dim-group 0 only)

    const int tid   = threadIdx.x;
    const int g     = blockIdx.x & 1;    // dim group: 0 -> dims 0..31, 1 -> 32..63
    const int chunk = blockIdx.x >> 1;

    float4* t4 = reinterpret_cast<float4*>(table);
    for (int i = tid; i < ACC_WORDS / 4; i += 512) t4[i] = make_float4(0.f, 0.f, 0.f, 0.f);
    if (g == 0)
        for (int i = tid; i < NCLASS; i += 512) hist[i] = 0;
    __syncthreads();

    const int row0 = chunk * rows_per_chunk;
    const int row1 = min(n, row0 + rows_per_chunk);
    const int sub  = tid & 7;            // which float4 of the 32-dim half
    const int rloc = tid >> 3;           // 0..63: row within the 64-row batch
    const int dbase = g * HALF + sub * 4;

    for (int r = row0 + rloc; r < row1; r += 64) {
        const int l = label[r];
        const float4 v = *reinterpret_cast<const float4*>(feat + (size_t)r * 64 + dbase);
        const int swz  = l & 31;
        const int base = l * HALF;
        const int w    = sub * 4;
        atomicAdd(&table[base + ((w + 0) ^ swz)], v.x);
        atomicAdd(&table[base + ((w + 1) ^ swz)], v.y);
        atomicAdd(&table[base + ((w + 2) ^ swz)], v.z);
        atomicAdd(&table[base + ((w + 3) ^ swz)], v.w);
        if (g == 0 && sub == 0) atomicAdd(&hist[l], 1);   // one count per row
    }
    __syncthreads();

    if (!atomic_mode) {
        // exclusive partial slot: un-swizzle while flushing (scalar stores;
        // permutation stays within one 128B line so writes still coalesce)
        float* slot = psums + (size_t)(g * nchunk + chunk) * ACC_WORDS;
        for (int i = tid; i < ACC_WORDS; i += 512) {
            const int c = i >> 5, dsw = i & 31;
            slot[(c << 5) | (dsw ^ (c & 31))] = table[i];
        }
    } else {
        // fallback: accumulate into d_out used as [NCLASS][64] sum buffer
        for (int i = tid; i < ACC_WORDS; i += 512) {
            const int c = i >> 5, dsw = i & 31;
            const float v = table[i];
            if (v != 0.0f) atomicAdd(&psums[c * 64 + g * HALF + (dsw ^ (c & 31))], v);
        }
    }
    if (g == 0) {
        for (int i = tid; i < NCLASS; i += 512)
            if (hist[i]) atomicAdd(&counts[i], hist[i]);
    }
}

// ---------------------------------------------------------------------------
// One wave (64 lanes) per class: reduce partials, mean, EMA logic.
__global__ void bank_finalize_kernel(const float* __restrict__ proto,
                                     const float* __restrict__ psums,
                                     const int* __restrict__ counts,
                                     const int* __restrict__ step_ptr,
                                     float* __restrict__ out,
                                     int nchunk, int atomic_mode)
{
    const int c = blockIdx.x * 4 + (threadIdx.x >> 6);   // 4 classes per 256-thr block
    const int d = threadIdx.x & 63;                      // dim = lane

    float s = 0.0f;
    if (!atomic_mode) {
        const int g = d >> 5, dd = d & 31;
        const float* base = psums + ((size_t)g * nchunk * NCLASS + c) * HALF + dd;
        #pragma unroll 4
        for (int k = 0; k < nchunk; ++k)
            s += base[(size_t)k * ACC_WORDS];
    } else {
        s = out[c * 64 + d];   // sums were atomically accumulated in-place
    }

    const int   cnt  = counts[c];
    const float mean = s / (float)(cnt > 0 ? cnt : 1);
    const float p    = proto[c * 64 + d];

    // zero_proto: all 64 dims of this class's prototype row are exactly 0
    const unsigned long long nzmask = __ballot(p != 0.0f);
    const bool use_new = (nzmask == 0ULL) || (step_ptr[0] <= WARMUP);

    const float lam = 0.9f;
    const float upd = use_new ? mean : (lam * p + (1.0f - lam) * mean);
    out[c * 64 + d] = (cnt > 0) ? upd : p;
}

// ---------------------------------------------------------------------------
extern "C" void kernel_launch(void* const* d_in, const int* in_sizes, int n_in,
                              void* d_out, int out_size, void* d_ws, size_t ws_size,
                              hipStream_t stream)
{
    const float* proto = (const float*)d_in[0];
    const float* feat  = (const float*)d_in[1];
    const int*   label = (const int*)d_in[2];
    const int*   step  = (const int*)d_in[3];
    float* out = (float*)d_out;
    const int n = in_sizes[2];

    int*   counts   = (int*)d_ws;                       // 4 KB
    float* partials = (float*)((char*)d_ws + 4096);     // 2*nchunk slots of 128 KB

    int nchunk = 128;
    while (nchunk > 1 &&
           (4096 + (size_t)2 * nchunk * ACC_WORDS * 4) > ws_size)
        nchunk >>= 1;
    const int atomic_mode =
        ((4096 + (size_t)2 * nchunk * ACC_WORDS * 4) > ws_size) ? 1 : 0;
    if (atomic_mode) nchunk = 128;   // ws too small: atomics into d_out instead

    bank_zero_kernel<<<(NCLASS + 255) / 256, 256, 0, stream>>>((float*)counts, NCLASS);
    if (atomic_mode)
        bank_zero_kernel<<<(NCLASS * 64 + 255) / 256, 256, 0, stream>>>(out, NCLASS * 64);

    const int rows_per = (n + nchunk - 1) / nchunk;
    bank_accum_kernel<<<2 * nchunk, 512, 0, stream>>>(
        feat, label, n, rows_per, nchunk,
        atomic_mode ? out : partials, counts, atomic_mode);

    bank_finalize_kernel<<<NCLASS / 4, 256, 0, stream>>>(
        proto, atomic_mode ? out : partials, counts, step, out, nchunk, atomic_mode);
}